// Round 5
// baseline (221.876 us; speedup 1.0000x reference)
//
#include <hip/hip_runtime.h>

namespace {
constexpr int BLOCK = 256;
constexpr int GRID = 1024;           // 4 blocks/CU, 16 waves/CU
constexpr float WPF = 4.0f;
constexpr float LN2 = 0.69314718055994531f;
constexpr float LOG2E = 1.44269504088896340f;
constexpr int COPIES = 16;                     // slot copies per wave (lane>>2): <=4-way atomic conflict
constexpr int NREG = (BLOCK / 64) * COPIES;    // 64 regions per block
constexpr int REGW = 25;                       // 5 classes x 5 fields
// fields: 0=cnt  1=D (sum of x4-xt, nat units)  2=li  3=nsel  4=liN
// global acc layout: acc[c*5 + f], 25 floats.
// Finalize only reads: cnt(all c), D(c<4), li(c<4), nsel(c<4), liN(c=4);
// rows with t==4 write li/nsel into slot4 which is never read -> masks on tc evaporate.
}

__global__ __launch_bounds__(BLOCK) void mpu_main(const float* __restrict__ x,
                                                  const int* __restrict__ t,
                                                  float* __restrict__ acc, int N) {
    __shared__ float slots[NREG * REGW];       // 6.4 KB
    for (int i = threadIdx.x; i < NREG * REGW; i += BLOCK) slots[i] = 0.0f;
    __syncthreads();

    const int region = (threadIdx.x >> 6) * COPIES + ((threadIdx.x & 63) >> 2);
    float* const myslot = &slots[region * REGW];

    // per row: 5 mul + 5 exp2 + 4 add + 1 log2 + 2 max3 + yt mul + 2 cmp +
    //          4 sub + 1 exp2 + 1 mul + 3 cndmask + 1 slot-addr  (~27 VALU, 7 trans)
    //          + 5 ds_add (class-routed, no masks) + gather (2 slots)
    auto process = [&](float x0, float x1, float x2, float x3, float x4,
                       float xt, int tc) {
        const float y0 = x0 * LOG2E, y1 = x1 * LOG2E, y2 = x2 * LOG2E,
                    y3 = x3 * LOG2E, y4 = x4 * LOG2E;
        // no max-subtraction: |x| < ~6.5 for N(0,1) inputs, exp2 range safe
        const float f0 = __builtin_amdgcn_exp2f(y0);
        const float f1 = __builtin_amdgcn_exp2f(y1);
        const float f2 = __builtin_amdgcn_exp2f(y2);
        const float f3 = __builtin_amdgcn_exp2f(y3);
        const float f4 = __builtin_amdgcn_exp2f(y4);
        const float s = ((f0 + f1) + (f2 + f3)) + f4;   // = sum e^{x_i}
        const float L2 = __builtin_amdgcn_logf(s);      // log2(s)
        const float thr = L2 - 1.0f;
        const float yt = xt * LOG2E;
        const float ymax = fmaxf(fmaxf(fmaxf(y0, y1), fmaxf(y2, y3)), y4);
        const bool sel = (yt > thr);                    // p_t > 0.5
        const bool alle = (ymax <= thr);                // all p <= 0.5
        const float nlnY = L2 - y4;                     // -log2(p_neg)
        const float cv = nlnY * __builtin_amdgcn_exp2f(L2 - yt);  // -log2(pneg)/p_t
        float* const sp = myslot + tc * 5;
        atomicAdd(sp + 0, 1.0f);                        // cnt_c
        atomicAdd(sp + 1, x4 - xt);                     // D (t==4 adds 0)
        atomicAdd(sp + 2, sel ? cv : 0.0f);             // li_c (slot4 unread)
        atomicAdd(sp + 3, sel ? 1.0f : 0.0f);           // nsel_c (slot4 unread)
        atomicAdd(sp + 4, alle ? nlnY : 0.0f);          // liN (slots 0..3 unread)
    };

    auto load_oct = [&](int g, float4 v[10], int4 tt[2]) {
        const float4* xv = reinterpret_cast<const float4*>(x) + (size_t)g * 10;
        const int4* tv = reinterpret_cast<const int4*>(t) + (size_t)g * 2;
#pragma unroll
        for (int j = 0; j < 10; ++j) v[j] = xv[j];
        tt[0] = tv[0];
        tt[1] = tv[1];
    };

    const int stride = gridDim.x * BLOCK;
    const int nOct = N >> 3;

    int g = blockIdx.x * BLOCK + threadIdx.x;
    float4 cv4[10];
    int4 ct[2];
    bool have = (g < nOct);
    if (have) load_oct(g, cv4, ct);
    while (have) {
        const int gn = g + stride;
        const bool haveN = (gn < nOct);
        float4 nv[10];
        int4 nt2[2];
        if (haveN) load_oct(gn, nv, nt2);      // next oct's loads in flight

        // gather xt for current 8 rows (L1 hits: same lines as cv4)
        const float* rb = x + (size_t)g * 40;
        float xt0 = rb[0 + ct[0].x], xt1 = rb[5 + ct[0].y];
        float xt2 = rb[10 + ct[0].z], xt3 = rb[15 + ct[0].w];
        float xt4 = rb[20 + ct[1].x], xt5 = rb[25 + ct[1].y];
        float xt6 = rb[30 + ct[1].z], xt7 = rb[35 + ct[1].w];

        process(cv4[0].x, cv4[0].y, cv4[0].z, cv4[0].w, cv4[1].x, xt0, ct[0].x);
        process(cv4[1].y, cv4[1].z, cv4[1].w, cv4[2].x, cv4[2].y, xt1, ct[0].y);
        process(cv4[2].z, cv4[2].w, cv4[3].x, cv4[3].y, cv4[3].z, xt2, ct[0].z);
        process(cv4[3].w, cv4[4].x, cv4[4].y, cv4[4].z, cv4[4].w, xt3, ct[0].w);
        process(cv4[5].x, cv4[5].y, cv4[5].z, cv4[5].w, cv4[6].x, xt4, ct[1].x);
        process(cv4[6].y, cv4[6].z, cv4[6].w, cv4[7].x, cv4[7].y, xt5, ct[1].y);
        process(cv4[7].z, cv4[7].w, cv4[8].x, cv4[8].y, cv4[8].z, xt6, ct[1].z);
        process(cv4[8].w, cv4[9].x, cv4[9].y, cv4[9].z, cv4[9].w, xt7, ct[1].w);

#pragma unroll
        for (int j = 0; j < 10; ++j) cv4[j] = nv[j];
        ct[0] = nt2[0];
        ct[1] = nt2[1];
        g = gn;
        have = haveN;
    }

    // tail rows (N % 8): single lane, writes its own region's slots
    if (blockIdx.x == 0 && threadIdx.x == 0) {
        for (int k = (N >> 3) << 3; k < N; ++k) {
            const int tk = t[k];
            process(x[k * 5 + 0], x[k * 5 + 1], x[k * 5 + 2], x[k * 5 + 3],
                    x[k * 5 + 4], x[k * 5 + tk], tk);
        }
    }

    __syncthreads();
    if (threadIdx.x < REGW) {
        float v = 0.0f;
#pragma unroll 8
        for (int r = 0; r < NREG; ++r) v += slots[r * REGW + threadIdx.x];
        atomicAdd(&acc[threadIdx.x], v);
    }
}

__global__ void mpu_final(const float* __restrict__ acc, float* __restrict__ out, int N) {
    if (threadIdx.x == 0 && blockIdx.x == 0) {
        const float invN = 1.0f / (float)N;
        // risk1 - risk3 = (1/N) * sum_{t<4} (x4 - xt)   [priors/denoms cancel exactly]
        const float risk13 = (acc[0 * 5 + 1] + acc[1 * 5 + 1] +
                              acc[2 * 5 + 1] + acc[3 * 5 + 1]) * invN;
        float risk2 = 0.0f;
#pragma unroll
        for (int c = 0; c < 4; ++c) {
            const float cnt = acc[c * 5 + 0];
            const float li = LN2 * acc[c * 5 + 2];          // log2 -> nat
            const float nsel = acc[c * 5 + 3];
            risk2 += (cnt * invN) * (li / fmaxf(nsel, 1.0f));
        }
        const float risk4 = LN2 * acc[4 * 5 + 4] / fmaxf(acc[4 * 5 + 0], 1.0f);
        float pos = WPF * (risk13 + risk2);
        if (pos < 0.0f) pos = 0.0f;
        out[0] = pos + risk4;
    }
}

extern "C" void kernel_launch(void* const* d_in, const int* in_sizes, int n_in,
                              void* d_out, int out_size, void* d_ws, size_t ws_size,
                              hipStream_t stream) {
    const float* x = (const float*)d_in[0];
    const int* t = (const int*)d_in[1];
    float* out = (float*)d_out;
    float* acc = (float*)d_ws;
    const int N = in_sizes[1];

    hipMemsetAsync(acc, 0, REGW * sizeof(float), stream);

    const int nOct = N >> 3;
    int grid = (nOct + BLOCK - 1) / BLOCK;
    if (grid > GRID) grid = GRID;
    if (grid < 1) grid = 1;
    mpu_main<<<grid, BLOCK, 0, stream>>>(x, t, acc, N);
    mpu_final<<<1, 64, 0, stream>>>(acc, out, N);
}

// Round 7
// 216.245 us; speedup vs baseline: 1.0260x; 1.0260x over previous
//
#include <hip/hip_runtime.h>

namespace {
constexpr int BLOCK = 256;
constexpr float WPF = 4.0f;
constexpr float LN2 = 0.69314718055994531f;
constexpr float LOG2E = 1.44269504088896340f;
// acc layout (ws): [0]=S13 (sum nltY-nlnY, t<4, log2 units)
// [1..4]=li_c (log2)  [5]=liN (log2)  [6..9]=cnt_c  [10..13]=nsel_c
// [14]=block-completion counter (uint)   -> memset 64 B zeroes all.
}

__device__ __forceinline__ float wave_reduce(float v) {
#pragma unroll
    for (int o = 32; o > 0; o >>= 1) v += __shfl_down(v, o, 64);
    return v;
}

__global__ __launch_bounds__(BLOCK) void mpu_main(const float* __restrict__ x,
                                                  const int* __restrict__ t,
                                                  float* __restrict__ acc,
                                                  float* __restrict__ out,
                                                  int N, int nblk) {
    __shared__ float red[BLOCK / 64][16];

    float S13 = 0.f, li0 = 0.f, li1 = 0.f, li2 = 0.f, li3 = 0.f, liN = 0.f;
    int c0 = 0, c1 = 0, c2 = 0, c3 = 0, n0 = 0, n1 = 0, n2 = 0, n3 = 0;

    // log2-domain throughout; no max-subtraction (|x|<~6.5 for N(0,1): exp2 safe)
    auto process = [&](float x0, float x1, float x2, float x3, float x4, int tc) {
        const float y0 = x0 * LOG2E, y1 = x1 * LOG2E, y2 = x2 * LOG2E,
                    y3 = x3 * LOG2E, y4 = x4 * LOG2E;
        const float f0 = __builtin_amdgcn_exp2f(y0);
        const float f1 = __builtin_amdgcn_exp2f(y1);
        const float f2 = __builtin_amdgcn_exp2f(y2);
        const float f3 = __builtin_amdgcn_exp2f(y3);
        const float f4 = __builtin_amdgcn_exp2f(y4);
        const float s = ((f0 + f1) + (f2 + f3)) + f4;    // sum e^{x_i}
        const float L2 = __builtin_amdgcn_logf(s);       // log2(sum)
        const float thr = L2 - 1.0f;
        // CORRECTNESS (R5 bug): without max-subtraction, "all p<=0.5" must be
        // tested as ymax <= log2(s)-1, NOT s>=2 (s is unnormalized here).
        const float ymax = fmaxf(fmaxf(fmaxf(y0, y1), fmaxf(y2, y3)), y4);
        const float yt = (tc == 0) ? y0 : (tc == 1) ? y1 : (tc == 2) ? y2
                       : (tc == 3) ? y3 : y4;
        const float nltY = L2 - yt;                      // -log2(p_t)
        const float nlnY = L2 - y4;                      // -log2(p_neg)
        const bool sel = (yt > thr);                     // p_t > 0.5
        const bool alle = (ymax <= thr);                 // all p <= 0.5
        const bool tpos = (tc < 4);
        // risk1-risk3 collapses to (LN2/N)*sum_{t<4}(nltY-nlnY)
        S13 += tpos ? (nltY - nlnY) : 0.f;
        const float cv = sel ? nlnY * __builtin_amdgcn_exp2f(nltY) : 0.f;
        li0 += (tc == 0) ? cv : 0.f;
        li1 += (tc == 1) ? cv : 0.f;
        li2 += (tc == 2) ? cv : 0.f;
        li3 += (tc == 3) ? cv : 0.f;
        liN += (tc == 4 && alle) ? nlnY : 0.f;

        const unsigned long long b0 = __ballot(tc == 0);
        const unsigned long long b1 = __ballot(tc == 1);
        const unsigned long long b2 = __ballot(tc == 2);
        const unsigned long long b3 = __ballot(tc == 3);
        const unsigned long long bs = __ballot(sel);
        c0 += (int)__popcll(b0);
        c1 += (int)__popcll(b1);
        c2 += (int)__popcll(b2);
        c3 += (int)__popcll(b3);
        n0 += (int)__popcll(bs & b0);
        n1 += (int)__popcll(bs & b1);
        n2 += (int)__popcll(bs & b2);
        n3 += (int)__popcll(bs & b3);
    };

    const int pid = blockIdx.x * BLOCK + threadIdx.x;    // one thread = 8 rows
    const int nOct = N >> 3;

    if (pid < nOct) {
        const float4* xv = reinterpret_cast<const float4*>(x) + (size_t)pid * 10;
        const int4* tv = reinterpret_cast<const int4*>(t) + (size_t)pid * 2;
        const float4 v0 = xv[0], v1 = xv[1], v2 = xv[2], v3 = xv[3], v4 = xv[4];
        const float4 v5 = xv[5], v6 = xv[6], v7 = xv[7], v8 = xv[8], v9 = xv[9];
        const int4 ta = tv[0], tb = tv[1];
        process(v0.x, v0.y, v0.z, v0.w, v1.x, ta.x);
        process(v1.y, v1.z, v1.w, v2.x, v2.y, ta.y);
        process(v2.z, v2.w, v3.x, v3.y, v3.z, ta.z);
        process(v3.w, v4.x, v4.y, v4.z, v4.w, ta.w);
        process(v5.x, v5.y, v5.z, v5.w, v6.x, tb.x);
        process(v6.y, v6.z, v6.w, v7.x, v7.y, tb.y);
        process(v7.z, v7.w, v8.x, v8.y, v8.z, tb.z);
        process(v8.w, v9.x, v9.y, v9.z, v9.w, tb.w);
    }
    // tail rows (N % 8): single lane; ballots correct under 1-lane exec
    if (blockIdx.x == 0 && threadIdx.x == 0) {
        for (int k = (N >> 3) << 3; k < N; ++k)
            process(x[k * 5 + 0], x[k * 5 + 1], x[k * 5 + 2], x[k * 5 + 3],
                    x[k * 5 + 4], t[k]);
    }

    const int wv = threadIdx.x >> 6, ln = threadIdx.x & 63;
    float fr[6] = {S13, li0, li1, li2, li3, liN};
#pragma unroll
    for (int j = 0; j < 6; ++j) {
        const float v = wave_reduce(fr[j]);
        if (ln == 0) red[wv][j] = v;
    }
    if (ln == 0) {   // counts are wave-uniform after ballot/popc
        red[wv][6] = (float)c0;   red[wv][7] = (float)c1;
        red[wv][8] = (float)c2;   red[wv][9] = (float)c3;
        red[wv][10] = (float)n0;  red[wv][11] = (float)n1;
        red[wv][12] = (float)n2;  red[wv][13] = (float)n3;
    }
    __syncthreads();
    if (threadIdx.x < 14) {
        const float v = red[0][threadIdx.x] + red[1][threadIdx.x] +
                        red[2][threadIdx.x] + red[3][threadIdx.x];
        atomicAdd(&acc[threadIdx.x], v);
    }
    __syncthreads();

    // last-block finalize (device-scope counter; coherent reads via atomicAdd 0)
    if (threadIdx.x == 0) {
        __threadfence();
        const unsigned old = atomicAdd((unsigned*)(acc + 14), 1u);
        if (old == (unsigned)nblk - 1u) {
            float a[14];
#pragma unroll
            for (int i = 0; i < 14; ++i) a[i] = atomicAdd(&acc[i], 0.0f);
            const float invN = 1.0f / (float)N;
            const float risk13 = LN2 * a[0] * invN;
            float risk2 = 0.0f;
#pragma unroll
            for (int c = 0; c < 4; ++c)
                risk2 += (a[6 + c] * invN) * (LN2 * a[1 + c] / fmaxf(a[10 + c], 1.0f));
            const float c4 = (float)N - (a[6] + a[7] + a[8] + a[9]);
            const float risk4 = LN2 * a[5] / fmaxf(c4, 1.0f);
            float pos = WPF * (risk13 + risk2);
            if (pos < 0.0f) pos = 0.0f;
            out[0] = pos + risk4;
        }
    }
}

extern "C" void kernel_launch(void* const* d_in, const int* in_sizes, int n_in,
                              void* d_out, int out_size, void* d_ws, size_t ws_size,
                              hipStream_t stream) {
    const float* x = (const float*)d_in[0];
    const int* t = (const int*)d_in[1];
    float* out = (float*)d_out;
    float* acc = (float*)d_ws;
    const int N = in_sizes[1];

    hipMemsetAsync(acc, 0, 64, stream);   // acc[0..13] + counter

    const int nOct = N >> 3;
    int grid = (nOct + BLOCK - 1) / BLOCK;
    if (grid < 1) grid = 1;
    mpu_main<<<grid, BLOCK, 0, stream>>>(x, t, acc, out, N, grid);
}

// Round 8
// 137.428 us; speedup vs baseline: 1.6145x; 1.5735x over previous
//
#include <hip/hip_runtime.h>

namespace {
constexpr int BLOCK = 256;
constexpr float WPF = 4.0f;
constexpr float LN2 = 0.69314718055994531f;
constexpr float LOG2E = 1.44269504088896340f;
// acc layout (ws, 14 floats): [0]=S13 (sum nltY-nlnY, t<4, log2 units)
// [1..4]=li_c (log2)  [5]=liN (log2)  [6..9]=cnt_c  [10..13]=nsel_c
// NOTE (R6 lesson): do NOT fuse the finalize into mpu_main with a per-block
// __threadfence() — agent-scope fences writeback/invalidate the per-XCD L2
// on gfx950 and cost ~80 us across ~2000 blocks. Separate launch is ~3 us.
}

__device__ __forceinline__ float wave_reduce(float v) {
#pragma unroll
    for (int o = 32; o > 0; o >>= 1) v += __shfl_down(v, o, 64);
    return v;
}

__global__ __launch_bounds__(BLOCK) void mpu_main(const float* __restrict__ x,
                                                  const int* __restrict__ t,
                                                  float* __restrict__ acc, int N) {
    __shared__ float red[BLOCK / 64][16];

    float S13 = 0.f, li0 = 0.f, li1 = 0.f, li2 = 0.f, li3 = 0.f, liN = 0.f;
    int c0 = 0, c1 = 0, c2 = 0, c3 = 0, n0 = 0, n1 = 0, n2 = 0, n3 = 0;

    // log2-domain; no max-subtraction (|x|<~6.5 for N(0,1): exp2-safe).
    auto process = [&](float x0, float x1, float x2, float x3, float x4, int tc) {
        const float y0 = x0 * LOG2E, y1 = x1 * LOG2E, y2 = x2 * LOG2E,
                    y3 = x3 * LOG2E, y4 = x4 * LOG2E;
        const float f0 = __builtin_amdgcn_exp2f(y0);
        const float f1 = __builtin_amdgcn_exp2f(y1);
        const float f2 = __builtin_amdgcn_exp2f(y2);
        const float f3 = __builtin_amdgcn_exp2f(y3);
        const float f4 = __builtin_amdgcn_exp2f(y4);
        const float s = ((f0 + f1) + (f2 + f3)) + f4;    // sum e^{x_i}
        const float L2 = __builtin_amdgcn_logf(s);       // log2(sum)
        const float thr = L2 - 1.0f;
        // "all p<=0.5" must be ymax <= log2(s)-1 when s is unnormalized (R5 bug).
        const float ymax = fmaxf(fmaxf(fmaxf(y0, y1), fmaxf(y2, y3)), y4);
        const float yt = (tc == 0) ? y0 : (tc == 1) ? y1 : (tc == 2) ? y2
                       : (tc == 3) ? y3 : y4;
        const float nltY = L2 - yt;                      // -log2(p_t)
        const float nlnY = L2 - y4;                      // -log2(p_neg)
        const bool sel = (yt > thr);                     // p_t > 0.5
        const bool alle = (ymax <= thr);                 // all p <= 0.5
        const bool tpos = (tc < 4);
        // risk1-risk3 collapses to (LN2/N)*sum_{t<4}(nltY-nlnY)
        S13 += tpos ? (nltY - nlnY) : 0.f;
        const float cv = sel ? nlnY * __builtin_amdgcn_exp2f(nltY) : 0.f;
        li0 += (tc == 0) ? cv : 0.f;
        li1 += (tc == 1) ? cv : 0.f;
        li2 += (tc == 2) ? cv : 0.f;
        li3 += (tc == 3) ? cv : 0.f;
        liN += (tc == 4 && alle) ? nlnY : 0.f;

        const unsigned long long b0 = __ballot(tc == 0);
        const unsigned long long b1 = __ballot(tc == 1);
        const unsigned long long b2 = __ballot(tc == 2);
        const unsigned long long b3 = __ballot(tc == 3);
        const unsigned long long bs = __ballot(sel);
        c0 += (int)__popcll(b0);
        c1 += (int)__popcll(b1);
        c2 += (int)__popcll(b2);
        c3 += (int)__popcll(b3);
        n0 += (int)__popcll(bs & b0);
        n1 += (int)__popcll(bs & b1);
        n2 += (int)__popcll(bs & b2);
        n3 += (int)__popcll(bs & b3);
    };

    const int pid = blockIdx.x * BLOCK + threadIdx.x;    // one thread = 8 rows
    const int nOct = N >> 3;

    if (pid < nOct) {
        const float4* xv = reinterpret_cast<const float4*>(x) + (size_t)pid * 10;
        const int4* tv = reinterpret_cast<const int4*>(t) + (size_t)pid * 2;
        const float4 v0 = xv[0], v1 = xv[1], v2 = xv[2], v3 = xv[3], v4 = xv[4];
        const float4 v5 = xv[5], v6 = xv[6], v7 = xv[7], v8 = xv[8], v9 = xv[9];
        const int4 ta = tv[0], tb = tv[1];
        process(v0.x, v0.y, v0.z, v0.w, v1.x, ta.x);
        process(v1.y, v1.z, v1.w, v2.x, v2.y, ta.y);
        process(v2.z, v2.w, v3.x, v3.y, v3.z, ta.z);
        process(v3.w, v4.x, v4.y, v4.z, v4.w, ta.w);
        process(v5.x, v5.y, v5.z, v5.w, v6.x, tb.x);
        process(v6.y, v6.z, v6.w, v7.x, v7.y, tb.y);
        process(v7.z, v7.w, v8.x, v8.y, v8.z, tb.z);
        process(v8.w, v9.x, v9.y, v9.z, v9.w, tb.w);
    }
    // tail rows (N % 8): single lane; ballots correct under 1-lane exec
    if (blockIdx.x == 0 && threadIdx.x == 0) {
        for (int k = (N >> 3) << 3; k < N; ++k)
            process(x[k * 5 + 0], x[k * 5 + 1], x[k * 5 + 2], x[k * 5 + 3],
                    x[k * 5 + 4], t[k]);
    }

    const int wv = threadIdx.x >> 6, ln = threadIdx.x & 63;
    float fr[6] = {S13, li0, li1, li2, li3, liN};
#pragma unroll
    for (int j = 0; j < 6; ++j) {
        const float v = wave_reduce(fr[j]);
        if (ln == 0) red[wv][j] = v;
    }
    if (ln == 0) {   // counts are wave-uniform after ballot/popc
        red[wv][6] = (float)c0;   red[wv][7] = (float)c1;
        red[wv][8] = (float)c2;   red[wv][9] = (float)c3;
        red[wv][10] = (float)n0;  red[wv][11] = (float)n1;
        red[wv][12] = (float)n2;  red[wv][13] = (float)n3;
    }
    __syncthreads();
    if (threadIdx.x < 14) {
        const float v = red[0][threadIdx.x] + red[1][threadIdx.x] +
                        red[2][threadIdx.x] + red[3][threadIdx.x];
        atomicAdd(&acc[threadIdx.x], v);   // device-scope by default; no fence
    }
}

__global__ void mpu_final(const float* __restrict__ acc, float* __restrict__ out, int N) {
    if (threadIdx.x == 0 && blockIdx.x == 0) {
        const float invN = 1.0f / (float)N;
        const float risk13 = LN2 * acc[0] * invN;   // risk1 - risk3 (exact collapse)
        float risk2 = 0.0f;
#pragma unroll
        for (int c = 0; c < 4; ++c)
            risk2 += (acc[6 + c] * invN) *
                     (LN2 * acc[1 + c] / fmaxf(acc[10 + c], 1.0f));
        const float c4 = (float)N - (acc[6] + acc[7] + acc[8] + acc[9]);
        const float risk4 = LN2 * acc[5] / fmaxf(c4, 1.0f);
        float pos = WPF * (risk13 + risk2);
        if (pos < 0.0f) pos = 0.0f;
        out[0] = pos + risk4;
    }
}

extern "C" void kernel_launch(void* const* d_in, const int* in_sizes, int n_in,
                              void* d_out, int out_size, void* d_ws, size_t ws_size,
                              hipStream_t stream) {
    const float* x = (const float*)d_in[0];
    const int* t = (const int*)d_in[1];
    float* out = (float*)d_out;
    float* acc = (float*)d_ws;
    const int N = in_sizes[1];

    hipMemsetAsync(acc, 0, 64, stream);

    const int nOct = N >> 3;
    int grid = (nOct + BLOCK - 1) / BLOCK;
    if (grid < 1) grid = 1;
    mpu_main<<<grid, BLOCK, 0, stream>>>(x, t, acc, N);
    mpu_final<<<1, 64, 0, stream>>>(acc, out, N);
}